// Round 6
// baseline (179.677 us; speedup 1.0000x reference)
//
#include <hip/hip_runtime.h>
#include <stdint.h>

// Sudoku naked-pair elimination as 9-bit candidate-set logic.
// mask: [B, 9 digit, 9 row, 9 col] fp32 binary, B = 32768 (729 floats/batch).
//
// Round-6: round-5 structure (ZERO barriers, ZERO LDS, one thread per 3x3
// box, whole pipeline in registers, 27 merged dwordx3 loads issued before
// any dependent use) with the erase step FIXED: exclusion must be by pair
// VALUE, not bitwise (two naked pairs can share a digit, e.g. {1,2} & {2,3}).

__global__ __launch_bounds__(256) void sudoku_box_kernel(
    const float* __restrict__ mask, float* __restrict__ out) {
  const int t = blockIdx.x * 256 + threadIdx.x;   // global box id
  const int board = t / 9;
  const int bi = t - board * 9;
  const int base = board * 729 + (bi / 3) * 27 + (bi % 3) * 3;

  // ---- Load the box's 81 elements (9 digit planes x 3 rows x 3 cols).
  // Each (d,r) triple is contiguous -> merged to global_load_dwordx3.
  const float* p = mask + base;
  float v[9][3][3];
#pragma unroll
  for (int d = 0; d < 9; ++d)
#pragma unroll
    for (int r = 0; r < 3; ++r)
#pragma unroll
      for (int c = 0; c < 3; ++c)
        v[d][r][c] = p[d * 81 + r * 9 + c];

  // ---- Candidate bitmask per cell
  uint32_t cellm[9] = {0, 0, 0, 0, 0, 0, 0, 0, 0};
#pragma unroll
  for (int d = 0; d < 9; ++d)
#pragma unroll
    for (int r = 0; r < 3; ++r)
#pragma unroll
      for (int c = 0; c < 3; ++c)
        cellm[r * 3 + c] |= (v[d][r][c] != 0.0f ? 1u : 0u) << d;

  // ---- Exact-pair mask per cell (nonzero iff popcount == 2)
  uint32_t pairm[9];
#pragma unroll
  for (int j = 0; j < 9; ++j)
    pairm[j] = (__popc(cellm[j]) == 2) ? cellm[j] : 0u;

  // ---- Naked iff exactly 2 cells in the box hold the same exact pair
  bool naked[9];
#pragma unroll
  for (int j = 0; j < 9; ++j) {
    int cnt = 0;
#pragma unroll
    for (int k = 0; k < 9; ++k) cnt += (pairm[k] == pairm[j]);
    naked[j] = (pairm[j] != 0u) && (cnt == 2);
  }

  // ---- Erase by VALUE: digit set pairm[k] erased from cell j iff naked[k]
  // and cell j is not itself an exact-pairm[k] cell.
  uint32_t fin[9];
#pragma unroll
  for (int j = 0; j < 9; ++j) {
    uint32_t er = 0;
#pragma unroll
    for (int k = 0; k < 9; ++k)
      if (naked[k] && pairm[k] != pairm[j]) er |= pairm[k];
    fin[j] = cellm[j] & ~er;
  }

  // ---- Write back 81 elements (27 merged dwordx3 stores)
  float* q = out + base;
#pragma unroll
  for (int d = 0; d < 9; ++d)
#pragma unroll
    for (int r = 0; r < 3; ++r)
#pragma unroll
      for (int c = 0; c < 3; ++c)
        q[d * 81 + r * 9 + c] = (float)((fin[r * 3 + c] >> d) & 1u);
}

extern "C" void kernel_launch(void* const* d_in, const int* in_sizes, int n_in,
                              void* d_out, int out_size, void* d_ws, size_t ws_size,
                              hipStream_t stream) {
  const float* mask = (const float*)d_in[0];
  // d_in[1] (enc) / d_in[2] (dec) are the fixed pair matrices; semantics hardcoded.
  float* out = (float*)d_out;
  const int B = in_sizes[0] / 729;      // 32768
  const int nbox = B * 9;               // 294912, divisible by 256
  const int grid = nbox / 256;          // 1152 blocks
  sudoku_box_kernel<<<grid, 256, 0, stream>>>(mask, out);
}